// Round 4
// baseline (225.215 us; speedup 1.0000x reference)
//
#include <hip/hip_runtime.h>

typedef __attribute__((ext_vector_type(8))) short bf16x8;
typedef __attribute__((ext_vector_type(4))) float floatx4;

__device__ __forceinline__ unsigned short f2bf(float f) {
    unsigned int u = __float_as_uint(f);
    u += 0x7FFFu + ((u >> 16) & 1u);
    return (unsigned short)(u >> 16);
}
__device__ __forceinline__ float bf2f(unsigned short h) {
    return __uint_as_float(((unsigned int)h) << 16);
}
__device__ __forceinline__ float rdlane_f(float v, int l) {
    return __uint_as_float((unsigned)__builtin_amdgcn_readlane(__float_as_uint(v), l));
}
__device__ __forceinline__ int rdlane_i(int v, int l) {
    return __builtin_amdgcn_readlane(v, l);
}

// ---- combined prep: [0,1024) x->NHWC bf16 | [1024,1312) Wk->bf16 [tap][oc][c] | [1312,1353) Woff ----
__global__ __launch_bounds__(256) void prep_all(const float* __restrict__ x,
        const float* __restrict__ Wk, const float* __restrict__ Woff,
        unsigned short* __restrict__ xt, unsigned short* __restrict__ Wkb,
        float* __restrict__ Wofft) {
    int bb = blockIdx.x;
    if (bb < 1024) {
        __shared__ float tile[64][65];
        int b = bb >> 6, y = bb & 63;
        const float* src = x + (size_t)b * 262144 + y * 64;   // + c*4096 + xc
        int tx = threadIdx.x & 15, tg = threadIdx.x >> 4;
#pragma unroll
        for (int i = 0; i < 4; i++) {
            int c = tg + i * 16;
            float4 v = *(const float4*)(src + (size_t)c * 4096 + tx * 4);
            tile[c][tx * 4 + 0] = v.x; tile[c][tx * 4 + 1] = v.y;
            tile[c][tx * 4 + 2] = v.z; tile[c][tx * 4 + 3] = v.w;
        }
        __syncthreads();
        unsigned short* dst = xt + (size_t)bb * 4096;   // [xc][c] bf16
#pragma unroll
        for (int i = 0; i < 4; i++) {
            int xc = tg + i * 16;
            int c4 = tx * 4;
            ushort4 v;
            v.x = f2bf(tile[c4 + 0][xc]); v.y = f2bf(tile[c4 + 1][xc]);
            v.z = f2bf(tile[c4 + 2][xc]); v.w = f2bf(tile[c4 + 3][xc]);
            *(ushort4*)(dst + xc * 64 + c4) = v;
        }
    } else if (bb < 1312) {
        int idx = (bb - 1024) * 256 + threadIdx.x;      // 73728 = [tap][oc][c]
        int c = idx & 63;
        int rest = idx >> 6;
        int oc = rest & 127;
        int tap = rest >> 7;
        Wkb[idx] = f2bf(Wk[(oc * 64 + c) * 9 + tap]);
    } else {
        int idx = (bb - 1312) * 256 + threadIdx.x;      // 10368 = [cin][tap][18]
        if (idx < 10368) {
            int n = idx % 18;
            int ct = idx / 18;
            int t = ct % 9;
            int cin = ct / 9;
            Wofft[idx] = Woff[(n * 64 + cin) * 9 + t];
        }
    }
}

// ---- offset conv: 8x8 px tile, wave = 16-ch group, LDS cross-wave reduce ----
__global__ __launch_bounds__(256) void offset_kernel(const float* __restrict__ x,
        const float* __restrict__ Wofft, const float* __restrict__ boff,
        float* __restrict__ off) {
    __shared__ float xs[4][1600];                       // 4 grp x 10x10x16 halo, 25.6 KB
    int tid = threadIdx.x;
    int wave = tid >> 6, lane = tid & 63;
    int py = lane >> 3, pxl = lane & 7;
    int tileX = blockIdx.x * 8, tileY = blockIdx.y * 8;
    int b = blockIdx.z;
    const float* xc0 = x + (size_t)(b * 64 + wave * 16) * 4096;
    for (int i = lane; i < 1600; i += 64) {
        int c = i / 100, rem = i - c * 100;
        int iy = rem / 10, ix = rem - iy * 10;
        int gy = tileY + iy - 1, gx = tileX + ix - 1;
        float v = 0.f;
        if (gy >= 0 && gy < 64 && gx >= 0 && gx < 64)
            v = xc0[c * 4096 + gy * 64 + gx];
        xs[wave][i] = v;
    }
    __syncthreads();
    float acc[18];
#pragma unroll
    for (int n = 0; n < 18; n++) acc[n] = 0.f;
    const float* wbase = Wofft + wave * 16 * 162;
    for (int c = 0; c < 16; c++) {
        const float* wc = wbase + c * 162;
        const float* xb = &xs[wave][c * 100 + py * 10 + pxl];
#pragma unroll
        for (int t = 0; t < 9; t++) {
            float xv = xb[(t / 3) * 10 + (t % 3)];
#pragma unroll
            for (int n = 0; n < 18; n++)
                acc[n] = fmaf(xv, wc[t * 18 + n], acc[n]);
        }
    }
    __syncthreads();                                    // xs reused as reduce buffer
    float* red = &xs[0][0];
    if (wave) {
#pragma unroll
        for (int n = 0; n < 18; n++)
            red[((wave - 1) * 64 + lane) * 18 + n] = acc[n];
    }
    __syncthreads();
    if (wave == 0) {
        int gyx = (tileY + py) * 64 + tileX + pxl;
        float* ob = off + (size_t)b * 73728 + gyx;
#pragma unroll
        for (int n = 0; n < 18; n++) {
            float v = acc[n] + red[lane * 18 + n] + red[(64 + lane) * 18 + n]
                    + red[(128 + lane) * 18 + n] + boff[n];
            ob[n << 12] = v;
        }
    }
}

// ---- fused bilinear-sample + GEMM: 64 px x 128 oc per block, XCD-local batches ----
__global__ __launch_bounds__(256) void fused_kernel(
        const unsigned short* __restrict__ xt,   // [b][y][x][c] bf16
        const float* __restrict__ off,           // [b][18][64][64]
        const unsigned short* __restrict__ Wkb,  // [tap][oc][c] bf16
        const float* __restrict__ bias,
        float* __restrict__ out) {
    __shared__ unsigned short As[128 * 72];      // [oc][k] 18.4 KB
    __shared__ unsigned short Bs[64 * 72];       // [px][c] 9.2 KB
    int tid = threadIdx.x;
    int wave = tid >> 6, lane = tid & 63;
    int wm = wave & 1, wn = wave >> 1;
    // XCD-aware remap: blockIdx%8 = XCD -> give each XCD 2 whole batch images
    int bb = blockIdx.x;
    int xcd = bb & 7, idx = bb >> 3;
    int b = xcd * 2 + (idx >> 6);
    int pxBase = (idx & 63) * 64;                // within-batch pixel base
    const unsigned short* img = xt + (size_t)b * 262144;
    const float* offb = off + (size_t)b * 73728;

    floatx4 acc[4][2];
#pragma unroll
    for (int i = 0; i < 4; i++)
#pragma unroll
        for (int j = 0; j < 2; j++)
            acc[i][j] = (floatx4)(0.f);

    int frow = lane & 15, fk = (lane >> 4) * 8;

    for (int tap = 0; tap < 9; tap++) {
        __syncthreads();
        // --- stage As: 128 oc x 64 c, fully coalesced ([tap][oc][c] layout) ---
        {
            int oc = tid >> 1, kh = (tid & 1) * 32;
            const unsigned short* srcw = Wkb + tap * 8192 + oc * 64 + kh;
            unsigned short* dstw = As + oc * 72 + kh;
#pragma unroll
            for (int i = 0; i < 4; i++)
                *(bf16x8*)(dstw + i * 8) = *(const bf16x8*)(srcw + i * 8);
        }
        // --- phase 1: lane p<16 computes bilinear for pixel wave*16+p ---
        float w00, w01, w10, w11;
        int o00, o01, o10, o11;
        {
            int p = lane & 15;
            int yx = pxBase + wave * 16 + p;
            int y = yx >> 6, xx = yx & 63;
            float orow = offb[tap * 4096 + yx];
            float ocol = offb[(9 + tap) * 4096 + yx];
            float pr = (float)(y + tap / 3 - 1) + orow;
            float pc = (float)(xx + tap % 3 - 1) + ocol;
            pr = fminf(fmaxf(pr, 0.f), 63.f);
            pc = fminf(fmaxf(pc, 0.f), 63.f);
            float fr = floorf(pr), fc = floorf(pc);
            float tr = pr - fr, tc = pc - fc;
            int r0 = (int)fr, c0 = (int)fc;
            int r1 = min(r0 + 1, 63), c1 = min(c0 + 1, 63);
            w00 = (1.f - tr) * (1.f - tc);
            w01 = (1.f - tr) * tc;
            w10 = tr * (1.f - tc);
            w11 = tr * tc;
            o00 = (r0 * 64 + c0) * 64;   // element offset of corner (channel 0)
            o01 = (r0 * 64 + c1) * 64;
            o10 = (r1 * 64 + c0) * 64;
            o11 = (r1 * 64 + c1) * 64;
        }
        // --- phase 2: 16 px x 64 ch into Bs (lane = channel, bf16 gathers) ---
        {
            unsigned short* brow = Bs + (wave * 16) * 72 + lane;
#pragma unroll 4
            for (int p = 0; p < 16; p++) {
                float a00 = rdlane_f(w00, p), a01 = rdlane_f(w01, p);
                float a10 = rdlane_f(w10, p), a11 = rdlane_f(w11, p);
                int   q00 = rdlane_i(o00, p), q01 = rdlane_i(o01, p);
                int   q10 = rdlane_i(o10, p), q11 = rdlane_i(o11, p);
                float v00 = bf2f(img[q00 + lane]);
                float v01 = bf2f(img[q01 + lane]);
                float v10 = bf2f(img[q10 + lane]);
                float v11 = bf2f(img[q11 + lane]);
                float v = a00 * v00 + a01 * v01 + a10 * v10 + a11 * v11;
                brow[p * 72] = f2bf(v);
            }
        }
        __syncthreads();
        // --- MFMA: 2 k-steps of 32 ---
#pragma unroll
        for (int kc = 0; kc < 2; kc++) {
            bf16x8 af[4], bf[2];
#pragma unroll
            for (int mt = 0; mt < 4; mt++)
                af[mt] = *(const bf16x8*)&As[(wm * 64 + mt * 16 + frow) * 72 + kc * 32 + fk];
#pragma unroll
            for (int nt = 0; nt < 2; nt++)
                bf[nt] = *(const bf16x8*)&Bs[(wn * 32 + nt * 16 + frow) * 72 + kc * 32 + fk];
#pragma unroll
            for (int mt = 0; mt < 4; mt++)
#pragma unroll
                for (int nt = 0; nt < 2; nt++)
                    acc[mt][nt] = __builtin_amdgcn_mfma_f32_16x16x32_bf16(
                        af[mt], bf[nt], acc[mt][nt], 0, 0, 0);
        }
    }

    // --- epilogue: D col=lane&15 (px), row=(lane>>4)*4+rg (oc) ---
    float* outb = out + (size_t)b * 524288;
#pragma unroll
    for (int mt = 0; mt < 4; mt++) {
#pragma unroll
        for (int nt = 0; nt < 2; nt++) {
            int px = pxBase + wn * 32 + nt * 16 + frow;
#pragma unroll
            for (int rg = 0; rg < 4; rg++) {
                int oc = wm * 64 + mt * 16 + (lane >> 4) * 4 + rg;
                outb[oc * 4096 + px] = acc[mt][nt][rg] + bias[oc];
            }
        }
    }
}

extern "C" void kernel_launch(void* const* d_in, const int* in_sizes, int n_in,
                              void* d_out, int out_size, void* d_ws, size_t ws_size,
                              hipStream_t stream) {
    const float* x    = (const float*)d_in[0];
    const float* Woff = (const float*)d_in[1];
    const float* boff = (const float*)d_in[2];
    const float* Wk   = (const float*)d_in[3];
    const float* bk   = (const float*)d_in[4];
    float* out = (float*)d_out;

    char* ws = (char*)d_ws;
    unsigned short* xt  = (unsigned short*)ws;                 // 8388608 B
    float* offb         = (float*)(ws + 8388608);              // 4718592 B
    unsigned short* Wkb = (unsigned short*)(ws + 13107200);    // 147456 B
    float* Wofft        = (float*)(ws + 13254656);             // 41472 B

    prep_all<<<1353, 256, 0, stream>>>(x, Wk, Woff, xt, Wkb, Wofft);
    offset_kernel<<<dim3(8, 8, 16), 256, 0, stream>>>(x, Wofft, boff, offb);
    fused_kernel<<<1024, 256, 0, stream>>>(xt, offb, Wkb, bk, out);
}

// Round 6
// 176.695 us; speedup vs baseline: 1.2746x; 1.2746x over previous
//
#include <hip/hip_runtime.h>

typedef __attribute__((ext_vector_type(8))) short bf16x8;
typedef __attribute__((ext_vector_type(4))) float floatx4;

__device__ __forceinline__ unsigned short f2bf(float f) {
    unsigned int u = __float_as_uint(f);
    u += 0x7FFFu + ((u >> 16) & 1u);
    return (unsigned short)(u >> 16);
}
__device__ __forceinline__ float bf2f(unsigned short h) {
    return __uint_as_float(((unsigned int)h) << 16);
}
__device__ __forceinline__ float rdlane_f(float v, int l) {
    return __uint_as_float((unsigned)__builtin_amdgcn_readlane(__float_as_uint(v), l));
}
__device__ __forceinline__ int rdlane_i(int v, int l) {
    return __builtin_amdgcn_readlane(v, l);
}

// ---- combined prep: [0,1024) x->NHWC bf16 | [1024,1312) Wk->bf16 [tap][oc][c] | [1312,1353) Woff ----
__global__ __launch_bounds__(256) void prep_all(const float* __restrict__ x,
        const float* __restrict__ Wk, const float* __restrict__ Woff,
        unsigned short* __restrict__ xt, unsigned short* __restrict__ Wkb,
        float* __restrict__ Wofft) {
    int bb = blockIdx.x;
    if (bb < 1024) {
        __shared__ float tile[64][65];
        int b = bb >> 6, y = bb & 63;
        const float* src = x + (size_t)b * 262144 + y * 64;   // + c*4096 + xc
        int tx = threadIdx.x & 15, tg = threadIdx.x >> 4;
#pragma unroll
        for (int i = 0; i < 4; i++) {
            int c = tg + i * 16;
            float4 v = *(const float4*)(src + (size_t)c * 4096 + tx * 4);
            tile[c][tx * 4 + 0] = v.x; tile[c][tx * 4 + 1] = v.y;
            tile[c][tx * 4 + 2] = v.z; tile[c][tx * 4 + 3] = v.w;
        }
        __syncthreads();
        unsigned short* dst = xt + (size_t)bb * 4096;   // [xc][c] bf16
#pragma unroll
        for (int i = 0; i < 4; i++) {
            int xc = tg + i * 16;
            int c4 = tx * 4;
            ushort4 v;
            v.x = f2bf(tile[c4 + 0][xc]); v.y = f2bf(tile[c4 + 1][xc]);
            v.z = f2bf(tile[c4 + 2][xc]); v.w = f2bf(tile[c4 + 3][xc]);
            *(ushort4*)(dst + xc * 64 + c4) = v;
        }
    } else if (bb < 1312) {
        int idx = (bb - 1024) * 256 + threadIdx.x;      // 73728 = [tap][oc][c]
        int c = idx & 63;
        int rest = idx >> 6;
        int oc = rest & 127;
        int tap = rest >> 7;
        Wkb[idx] = f2bf(Wk[(oc * 64 + c) * 9 + tap]);
    } else {
        int idx = (bb - 1312) * 256 + threadIdx.x;      // 10368 = [cin][tap][18]
        if (idx < 10368) {
            int n = idx % 18;
            int ct = idx / 18;
            int t = ct % 9;
            int cin = ct / 9;
            Wofft[idx] = Woff[(n * 64 + cin) * 9 + t];
        }
    }
}

// ---- offset conv: 8x8 px tile, wave = 16-ch group (readfirstlane-scalarized
//      so weight loads are s_load + SGPR fmac operands), LDS cross-wave reduce ----
__global__ __launch_bounds__(256) void offset_kernel(const float* __restrict__ x,
        const float* __restrict__ Wofft, const float* __restrict__ boff,
        float* __restrict__ off) {
    __shared__ float xs[4][1600];                       // 4 grp x 10x10x16 halo, 25.6 KB
    int tid = threadIdx.x;
    int lane = tid & 63;
    int wgrp = __builtin_amdgcn_readfirstlane(tid >> 6);   // wave index, provably uniform
    int py = lane >> 3, pxl = lane & 7;
    int tileX = blockIdx.x * 8, tileY = blockIdx.y * 8;
    int b = blockIdx.z;
    const float* xc0 = x + (size_t)(b * 64 + wgrp * 16) * 4096;
    for (int i = lane; i < 1600; i += 64) {
        int c = i / 100, rem = i - c * 100;
        int iy = rem / 10, ix = rem - iy * 10;
        int gy = tileY + iy - 1, gx = tileX + ix - 1;
        float v = 0.f;
        if (gy >= 0 && gy < 64 && gx >= 0 && gx < 64)
            v = xc0[c * 4096 + gy * 64 + gx];
        xs[wgrp][i] = v;
    }
    __syncthreads();
    float acc[18];
#pragma unroll
    for (int n = 0; n < 18; n++) acc[n] = 0.f;
    const float* wbase = Wofft + wgrp * (16 * 162);     // uniform -> s_load weights
    for (int c = 0; c < 16; c++) {
        const float* wc = wbase + c * 162;
        const float* xb = &xs[wgrp][c * 100 + py * 10 + pxl];
#pragma unroll
        for (int t = 0; t < 9; t++) {
            float xv = xb[(t / 3) * 10 + (t % 3)];
#pragma unroll
            for (int n = 0; n < 18; n++)
                acc[n] = fmaf(xv, wc[t * 18 + n], acc[n]);
        }
    }
    __syncthreads();                                    // xs reused as reduce buffer
    float* red = &xs[0][0];
    if (wgrp) {
#pragma unroll
        for (int n = 0; n < 18; n++)
            red[((wgrp - 1) * 64 + lane) * 18 + n] = acc[n];
    }
    __syncthreads();
    if (wgrp == 0) {
        int gyx = (tileY + py) * 64 + tileX + pxl;
        float* ob = off + (size_t)b * 73728 + gyx;
#pragma unroll
        for (int n = 0; n < 18; n++) {
            float v = acc[n] + red[lane * 18 + n] + red[(64 + lane) * 18 + n]
                    + red[(128 + lane) * 18 + n] + boff[n];
            ob[n << 12] = v;
        }
    }
}

// ---- fused bilinear-sample + GEMM: 128 px x 128 oc per block, 8 waves,
//      XCD-local batches (2 images per XCD, L2-resident bf16) ----
__global__ __launch_bounds__(512, 4) void fused_kernel(
        const unsigned short* __restrict__ xt,   // [b][y][x][c] bf16
        const float* __restrict__ off,           // [b][18][64][64]
        const unsigned short* __restrict__ Wkb,  // [tap][oc][c] bf16
        const float* __restrict__ bias,
        float* __restrict__ out) {
    __shared__ unsigned short As[128 * 72];      // [oc][k] 18.4 KB
    __shared__ unsigned short Bs[128 * 72];      // [px][c] 18.4 KB
    int tid = threadIdx.x;
    int wave = tid >> 6, lane = tid & 63;
    int wm = wave & 1, wn = wave >> 1;           // wm: oc 64-half, wn: px 32-quarter
    // XCD-aware remap: blockIdx%8 = XCD -> 2 whole batch images per XCD
    int bb = blockIdx.x;
    int xcd = bb & 7, idx = bb >> 3;
    int b = xcd * 2 + (idx >> 5);
    int pxBase = (idx & 31) * 128;               // within-batch pixel base
    const unsigned short* img = xt + (size_t)b * 262144;
    const float* offb = off + (size_t)b * 73728;

    floatx4 acc[4][2];
#pragma unroll
    for (int i = 0; i < 4; i++)
#pragma unroll
        for (int j = 0; j < 2; j++)
            acc[i][j] = (floatx4)(0.f);

    int frow = lane & 15, fk = (lane >> 4) * 8;

    for (int tap = 0; tap < 9; tap++) {
        __syncthreads();
        // --- stage As: 128 oc x 64 c; 512 threads x 16 elem = 8192 elem exactly ---
        {
            int oc = tid >> 2, ke = (tid & 3) * 16;
            const unsigned short* srcw = Wkb + tap * 8192 + oc * 64 + ke;
            unsigned short* dstw = As + oc * 72 + ke;
            *(bf16x8*)(dstw)     = *(const bf16x8*)(srcw);
            *(bf16x8*)(dstw + 8) = *(const bf16x8*)(srcw + 8);
        }
        // --- phase 1: lane p<16 computes bilinear for pixel wave*16+p ---
        float w00, w01, w10, w11;
        int o00, o01, o10, o11;
        {
            int p = lane & 15;
            int yx = pxBase + wave * 16 + p;
            int y = yx >> 6, xx = yx & 63;
            float orow = offb[tap * 4096 + yx];
            float ocol = offb[(9 + tap) * 4096 + yx];
            float pr = (float)(y + tap / 3 - 1) + orow;
            float pc = (float)(xx + tap % 3 - 1) + ocol;
            pr = fminf(fmaxf(pr, 0.f), 63.f);
            pc = fminf(fmaxf(pc, 0.f), 63.f);
            float fr = floorf(pr), fc = floorf(pc);
            float tr = pr - fr, tc = pc - fc;
            int r0 = (int)fr, c0 = (int)fc;
            int r1 = min(r0 + 1, 63), c1 = min(c0 + 1, 63);
            w00 = (1.f - tr) * (1.f - tc);
            w01 = (1.f - tr) * tc;
            w10 = tr * (1.f - tc);
            w11 = tr * tc;
            o00 = (r0 * 64 + c0) * 64;   // element offset of corner (channel 0)
            o01 = (r0 * 64 + c1) * 64;
            o10 = (r1 * 64 + c0) * 64;
            o11 = (r1 * 64 + c1) * 64;
        }
        // --- phase 2: 16 px x 64 ch into Bs (lane = channel, bf16 gathers) ---
        {
            unsigned short* brow = Bs + (wave * 16) * 72 + lane;
#pragma unroll 8
            for (int p = 0; p < 16; p++) {
                float a00 = rdlane_f(w00, p), a01 = rdlane_f(w01, p);
                float a10 = rdlane_f(w10, p), a11 = rdlane_f(w11, p);
                int   q00 = rdlane_i(o00, p), q01 = rdlane_i(o01, p);
                int   q10 = rdlane_i(o10, p), q11 = rdlane_i(o11, p);
                float v00 = bf2f(img[q00 + lane]);
                float v01 = bf2f(img[q01 + lane]);
                float v10 = bf2f(img[q10 + lane]);
                float v11 = bf2f(img[q11 + lane]);
                float v = a00 * v00 + a01 * v01 + a10 * v10 + a11 * v11;
                brow[p * 72] = f2bf(v);
            }
        }
        __syncthreads();
        // --- MFMA: 2 k-steps of 32 over this tap's 64-wide slice ---
#pragma unroll
        for (int kc = 0; kc < 2; kc++) {
            bf16x8 af[4], bf[2];
#pragma unroll
            for (int mt = 0; mt < 4; mt++)
                af[mt] = *(const bf16x8*)&As[(wm * 64 + mt * 16 + frow) * 72 + kc * 32 + fk];
#pragma unroll
            for (int nt = 0; nt < 2; nt++)
                bf[nt] = *(const bf16x8*)&Bs[(wn * 32 + nt * 16 + frow) * 72 + kc * 32 + fk];
#pragma unroll
            for (int mt = 0; mt < 4; mt++)
#pragma unroll
                for (int nt = 0; nt < 2; nt++)
                    acc[mt][nt] = __builtin_amdgcn_mfma_f32_16x16x32_bf16(
                        af[mt], bf[nt], acc[mt][nt], 0, 0, 0);
        }
    }

    // --- epilogue: D col=lane&15 (px), row=(lane>>4)*4+rg (oc) ---
    float* outb = out + (size_t)b * 524288;
#pragma unroll
    for (int mt = 0; mt < 4; mt++) {
#pragma unroll
        for (int nt = 0; nt < 2; nt++) {
            int px = pxBase + wn * 32 + nt * 16 + frow;
#pragma unroll
            for (int rg = 0; rg < 4; rg++) {
                int oc = wm * 64 + mt * 16 + (lane >> 4) * 4 + rg;
                outb[oc * 4096 + px] = acc[mt][nt][rg] + bias[oc];
            }
        }
    }
}

extern "C" void kernel_launch(void* const* d_in, const int* in_sizes, int n_in,
                              void* d_out, int out_size, void* d_ws, size_t ws_size,
                              hipStream_t stream) {
    const float* x    = (const float*)d_in[0];
    const float* Woff = (const float*)d_in[1];
    const float* boff = (const float*)d_in[2];
    const float* Wk   = (const float*)d_in[3];
    const float* bk   = (const float*)d_in[4];
    float* out = (float*)d_out;

    char* ws = (char*)d_ws;
    unsigned short* xt  = (unsigned short*)ws;                 // 8388608 B
    float* offb         = (float*)(ws + 8388608);              // 4718592 B
    unsigned short* Wkb = (unsigned short*)(ws + 13107200);    // 147456 B
    float* Wofft        = (float*)(ws + 13254656);             // 41472 B

    prep_all<<<1353, 256, 0, stream>>>(x, Wk, Woff, xt, Wkb, Wofft);
    offset_kernel<<<dim3(8, 8, 16), 256, 0, stream>>>(x, Wofft, boff, offb);
    fused_kernel<<<512, 512, 0, stream>>>(xt, offb, Wkb, bk, out);
}

// Round 7
// 158.096 us; speedup vs baseline: 1.4245x; 1.1176x over previous
//
#include <hip/hip_runtime.h>

typedef __attribute__((ext_vector_type(8))) short bf16x8;
typedef __attribute__((ext_vector_type(4))) float floatx4;

__device__ __forceinline__ unsigned short f2bf(float f) {
    unsigned int u = __float_as_uint(f);
    u += 0x7FFFu + ((u >> 16) & 1u);
    return (unsigned short)(u >> 16);
}

// ---- combined prep: [0,1024) x->NHWC bf16 | [1024,1312) Wk->bf16 [tap][oc][c] | [1312,1353) Woff ----
__global__ __launch_bounds__(256) void prep_all(const float* __restrict__ x,
        const float* __restrict__ Wk, const float* __restrict__ Woff,
        unsigned short* __restrict__ xt, unsigned short* __restrict__ Wkb,
        float* __restrict__ Wofft) {
    int bb = blockIdx.x;
    if (bb < 1024) {
        __shared__ float tile[64][65];
        int b = bb >> 6, y = bb & 63;
        const float* src = x + (size_t)b * 262144 + y * 64;   // + c*4096 + xc
        int tx = threadIdx.x & 15, tg = threadIdx.x >> 4;
#pragma unroll
        for (int i = 0; i < 4; i++) {
            int c = tg + i * 16;
            float4 v = *(const float4*)(src + (size_t)c * 4096 + tx * 4);
            tile[c][tx * 4 + 0] = v.x; tile[c][tx * 4 + 1] = v.y;
            tile[c][tx * 4 + 2] = v.z; tile[c][tx * 4 + 3] = v.w;
        }
        __syncthreads();
        unsigned short* dst = xt + (size_t)bb * 4096;   // [xc][c] bf16
#pragma unroll
        for (int i = 0; i < 4; i++) {
            int xc = tg + i * 16;
            int c4 = tx * 4;
            ushort4 v;
            v.x = f2bf(tile[c4 + 0][xc]); v.y = f2bf(tile[c4 + 1][xc]);
            v.z = f2bf(tile[c4 + 2][xc]); v.w = f2bf(tile[c4 + 3][xc]);
            *(ushort4*)(dst + xc * 64 + c4) = v;
        }
    } else if (bb < 1312) {
        int idx = (bb - 1024) * 256 + threadIdx.x;      // 73728 = [tap][oc][c]
        int c = idx & 63;
        int rest = idx >> 6;
        int oc = rest & 127;
        int tap = rest >> 7;
        Wkb[idx] = f2bf(Wk[(oc * 64 + c) * 9 + tap]);
    } else {
        int idx = (bb - 1312) * 256 + threadIdx.x;      // 10368 = [cin][tap][18]
        if (idx < 10368) {
            int n = idx % 18;
            int ct = idx / 18;
            int t = ct % 9;
            int cin = ct / 9;
            Wofft[idx] = Woff[(n * 64 + cin) * 9 + t];
        }
    }
}

// ---- offset conv: 8x8 px tile, wave = 16-ch group (readfirstlane-scalarized
//      so weight loads are s_load + SGPR fmac operands), LDS cross-wave reduce ----
__global__ __launch_bounds__(256) void offset_kernel(const float* __restrict__ x,
        const float* __restrict__ Wofft, const float* __restrict__ boff,
        float* __restrict__ off) {
    __shared__ float xs[4][1600];                       // 4 grp x 10x10x16 halo, 25.6 KB
    int tid = threadIdx.x;
    int lane = tid & 63;
    int wgrp = __builtin_amdgcn_readfirstlane(tid >> 6);   // wave index, provably uniform
    int py = lane >> 3, pxl = lane & 7;
    int tileX = blockIdx.x * 8, tileY = blockIdx.y * 8;
    int b = blockIdx.z;
    const float* xc0 = x + (size_t)(b * 64 + wgrp * 16) * 4096;
    for (int i = lane; i < 1600; i += 64) {
        int c = i / 100, rem = i - c * 100;
        int iy = rem / 10, ix = rem - iy * 10;
        int gy = tileY + iy - 1, gx = tileX + ix - 1;
        float v = 0.f;
        if (gy >= 0 && gy < 64 && gx >= 0 && gx < 64)
            v = xc0[c * 4096 + gy * 64 + gx];
        xs[wgrp][i] = v;
    }
    __syncthreads();
    float acc[18];
#pragma unroll
    for (int n = 0; n < 18; n++) acc[n] = 0.f;
    const float* wbase = Wofft + wgrp * (16 * 162);     // uniform -> s_load weights
    for (int c = 0; c < 16; c++) {
        const float* wc = wbase + c * 162;
        const float* xb = &xs[wgrp][c * 100 + py * 10 + pxl];
#pragma unroll
        for (int t = 0; t < 9; t++) {
            float xv = xb[(t / 3) * 10 + (t % 3)];
#pragma unroll
            for (int n = 0; n < 18; n++)
                acc[n] = fmaf(xv, wc[t * 18 + n], acc[n]);
        }
    }
    __syncthreads();                                    // xs reused as reduce buffer
    float* red = &xs[0][0];
    if (wgrp) {
#pragma unroll
        for (int n = 0; n < 18; n++)
            red[((wgrp - 1) * 64 + lane) * 18 + n] = acc[n];
    }
    __syncthreads();
    if (wgrp == 0) {
        int gyx = (tileY + py) * 64 + tileX + pxl;
        float* ob = off + (size_t)b * 73728 + gyx;
#pragma unroll
        for (int n = 0; n < 18; n++) {
            float v = acc[n] + red[lane * 18 + n] + red[(64 + lane) * 18 + n]
                    + red[(128 + lane) * 18 + n] + boff[n];
            ob[n << 12] = v;
        }
    }
}

// ---- fused sample+GEMM, register-direct B fragments ----
// Wave owns 16 px (n = lane&15) x 128 oc. Corner gathers land directly in
// MFMA B-operand layout: one dwordx4 = 1 corner x 16px x 32ch. No Bs LDS.
__global__ __launch_bounds__(256, 4) void fused_kernel(
        const unsigned short* __restrict__ xt,   // [b][y][x][c] bf16
        const float* __restrict__ off,           // [b][18][64][64]
        const unsigned short* __restrict__ Wkb,  // [tap][oc][c] bf16
        const float* __restrict__ bias,
        float* __restrict__ out) {
    __shared__ unsigned short As[128 * 72];      // [oc][k] 18.4 KB
    int tid = threadIdx.x;
    int wave = tid >> 6, lane = tid & 63;
    int frow = lane & 15, quad = lane >> 4;
    // XCD-aware remap: 2 whole batch images per XCD (img+off L2-resident)
    int bb = blockIdx.x;
    int xcd = bb & 7, idx = bb >> 3;
    int b = xcd * 2 + (idx >> 6);
    int pxBase = (idx & 63) * 64;
    int px = pxBase + wave * 16 + frow;          // this lane's pixel (B-frag n-index)
    const char* img = (const char*)(xt + (size_t)b * 262144) + quad * 16;
    const float* offb = off + (size_t)b * 73728;

    floatx4 acc[8];
#pragma unroll
    for (int i = 0; i < 8; i++) acc[i] = (floatx4)(0.f);

    int fk = quad * 8;
    int y = px >> 6, xx = px & 63;

    for (int tap = 0; tap < 9; tap++) {
        __syncthreads();
        // --- stage As: 128 oc x 64 ch; 256 threads x 32 elems, coalesced 64B/thread ---
        {
            int oc = tid >> 1, seg = (tid & 1) * 32;
            const unsigned short* srcw = Wkb + tap * 8192 + oc * 64 + seg;
            unsigned short* dstw = As + oc * 72 + seg;
#pragma unroll
            for (int i = 0; i < 4; i++)
                *(bf16x8*)(dstw + i * 8) = *(const bf16x8*)(srcw + i * 8);
        }
        __syncthreads();
        // --- per-lane bilinear params for this lane's pixel ---
        float orow = offb[tap * 4096 + px];
        float ocol = offb[(9 + tap) * 4096 + px];
        float pr = (float)(y + tap / 3 - 1) + orow;
        float pc = (float)(xx + tap % 3 - 1) + ocol;
        pr = fminf(fmaxf(pr, 0.f), 63.f);
        pc = fminf(fmaxf(pc, 0.f), 63.f);
        float fr = floorf(pr), fc = floorf(pc);
        float tr = pr - fr, tc = pc - fc;
        int r0 = (int)fr, c0 = (int)fc;
        int r1 = min(r0 + 1, 63), c1 = min(c0 + 1, 63);
        float w00 = (1.f - tr) * (1.f - tc);
        float w01 = (1.f - tr) * tc;
        float w10 = tr * (1.f - tc);
        float w11 = tr * tc;
        int o00 = (r0 * 64 + c0) * 128;          // byte offset of corner row
        int o01 = (r0 * 64 + c1) * 128;
        int o10 = (r1 * 64 + c0) * 128;
        int o11 = (r1 * 64 + c1) * 128;

        // --- gather 4 corners x 2 k-steps (each load: 16px x 32ch in B-frag order) ---
        bf16x8 bfrag[2];
#pragma unroll
        for (int kc = 0; kc < 2; kc++) {
            int4 u00 = __builtin_bit_cast(int4, *(const bf16x8*)(img + o00 + kc * 64));
            int4 u01 = __builtin_bit_cast(int4, *(const bf16x8*)(img + o01 + kc * 64));
            int4 u10 = __builtin_bit_cast(int4, *(const bf16x8*)(img + o10 + kc * 64));
            int4 u11 = __builtin_bit_cast(int4, *(const bf16x8*)(img + o11 + kc * 64));
            int4 r;
#pragma unroll
            for (int wd = 0; wd < 4; wd++) {
                int a00 = (wd == 0) ? u00.x : (wd == 1) ? u00.y : (wd == 2) ? u00.z : u00.w;
                int a01 = (wd == 0) ? u01.x : (wd == 1) ? u01.y : (wd == 2) ? u01.z : u01.w;
                int a10 = (wd == 0) ? u10.x : (wd == 1) ? u10.y : (wd == 2) ? u10.z : u10.w;
                int a11 = (wd == 0) ? u11.x : (wd == 1) ? u11.y : (wd == 2) ? u11.z : u11.w;
                float vl = w00 * __uint_as_float((unsigned)a00 << 16)
                         + w01 * __uint_as_float((unsigned)a01 << 16)
                         + w10 * __uint_as_float((unsigned)a10 << 16)
                         + w11 * __uint_as_float((unsigned)a11 << 16);
                float vh = w00 * __uint_as_float((unsigned)a00 & 0xffff0000u)
                         + w01 * __uint_as_float((unsigned)a01 & 0xffff0000u)
                         + w10 * __uint_as_float((unsigned)a10 & 0xffff0000u)
                         + w11 * __uint_as_float((unsigned)a11 & 0xffff0000u);
                unsigned pk = __builtin_amdgcn_perm(
                    __float_as_uint(vh) + 0x8000u,
                    __float_as_uint(vl) + 0x8000u, 0x07060302u);
                if (wd == 0) r.x = (int)pk; else if (wd == 1) r.y = (int)pk;
                else if (wd == 2) r.z = (int)pk; else r.w = (int)pk;
            }
            bfrag[kc] = __builtin_bit_cast(bf16x8, r);
        }
        // --- MFMA: 8 oc-tiles x 2 k-steps, A from LDS, B from registers ---
#pragma unroll
        for (int kc = 0; kc < 2; kc++) {
#pragma unroll
            for (int mt = 0; mt < 8; mt++) {
                bf16x8 af = *(const bf16x8*)&As[(mt * 16 + frow) * 72 + kc * 32 + fk];
                acc[mt] = __builtin_amdgcn_mfma_f32_16x16x32_bf16(af, bfrag[kc], acc[mt], 0, 0, 0);
            }
        }
    }

    // --- epilogue: D col=lane&15 (px ✓), row=quad*4+rg (oc) ---
    float* outb = out + (size_t)b * 524288 + px;
#pragma unroll
    for (int mt = 0; mt < 8; mt++) {
#pragma unroll
        for (int rg = 0; rg < 4; rg++) {
            int oc = mt * 16 + quad * 4 + rg;
            outb[oc * 4096] = acc[mt][rg] + bias[oc];
        }
    }
}

extern "C" void kernel_launch(void* const* d_in, const int* in_sizes, int n_in,
                              void* d_out, int out_size, void* d_ws, size_t ws_size,
                              hipStream_t stream) {
    const float* x    = (const float*)d_in[0];
    const float* Woff = (const float*)d_in[1];
    const float* boff = (const float*)d_in[2];
    const float* Wk   = (const float*)d_in[3];
    const float* bk   = (const float*)d_in[4];
    float* out = (float*)d_out;

    char* ws = (char*)d_ws;
    unsigned short* xt  = (unsigned short*)ws;                 // 8388608 B
    float* offb         = (float*)(ws + 8388608);              // 4718592 B
    unsigned short* Wkb = (unsigned short*)(ws + 13107200);    // 147456 B
    float* Wofft        = (float*)(ws + 13254656);             // 41472 B

    prep_all<<<1353, 256, 0, stream>>>(x, Wk, Woff, xt, Wkb, Wofft);
    offset_kernel<<<dim3(8, 8, 16), 256, 0, stream>>>(x, Wofft, boff, offb);
    fused_kernel<<<1024, 256, 0, stream>>>(xt, offb, Wkb, bk, out);
}

// Round 8
// 132.275 us; speedup vs baseline: 1.7026x; 1.1952x over previous
//
#include <hip/hip_runtime.h>

typedef __attribute__((ext_vector_type(8))) short bf16x8;
typedef __attribute__((ext_vector_type(4))) float floatx4;

__device__ __forceinline__ unsigned short f2bf(float f) {
    unsigned int u = __float_as_uint(f);
    u += 0x7FFFu + ((u >> 16) & 1u);
    return (unsigned short)(u >> 16);
}

// ---- prep: [0,1024) x->NHWC bf16 | [1024,1312) Wk frag-major | [1312,1384) Woff frag-major ----
// Fragment-major: elem (tap, tile=mt*2+kc, lane, j) at flat [tap*T + tile*512 + lane*8 + j],
// holding W[row = mt*16 + (lane&15)][k = kc*32 + (lane>>4)*8 + j] for that tap.
__global__ __launch_bounds__(256) void prep_all(const float* __restrict__ x,
        const float* __restrict__ Wk, const float* __restrict__ Woff,
        unsigned short* __restrict__ xt, unsigned short* __restrict__ Wkb2,
        unsigned short* __restrict__ Woffb) {
    int bb = blockIdx.x;
    if (bb < 1024) {
        __shared__ float tile[64][65];
        int b = bb >> 6, y = bb & 63;
        const float* src = x + (size_t)b * 262144 + y * 64;   // + c*4096 + xc
        int tx = threadIdx.x & 15, tg = threadIdx.x >> 4;
#pragma unroll
        for (int i = 0; i < 4; i++) {
            int c = tg + i * 16;
            float4 v = *(const float4*)(src + (size_t)c * 4096 + tx * 4);
            tile[c][tx * 4 + 0] = v.x; tile[c][tx * 4 + 1] = v.y;
            tile[c][tx * 4 + 2] = v.z; tile[c][tx * 4 + 3] = v.w;
        }
        __syncthreads();
        unsigned short* dst = xt + (size_t)bb * 4096;   // [xc][c] bf16
#pragma unroll
        for (int i = 0; i < 4; i++) {
            int xc = tg + i * 16;
            int c4 = tx * 4;
            ushort4 v;
            v.x = f2bf(tile[c4 + 0][xc]); v.y = f2bf(tile[c4 + 1][xc]);
            v.z = f2bf(tile[c4 + 2][xc]); v.w = f2bf(tile[c4 + 3][xc]);
            *(ushort4*)(dst + xc * 64 + c4) = v;
        }
    } else if (bb < 1312) {
        int idx = (bb - 1024) * 256 + threadIdx.x;      // [0, 73728): 9 taps x 16 tiles x 512
        int tap = idx >> 13;
        int r = idx & 8191;
        int tile = r >> 9;
        int ln = (r >> 3) & 63;
        int j = r & 7;
        int mt = tile >> 1, kc = tile & 1;
        int oc = mt * 16 + (ln & 15);
        int c = kc * 32 + (ln >> 4) * 8 + j;
        Wkb2[idx] = f2bf(Wk[(oc * 64 + c) * 9 + tap]);
    } else {
        int idx = (bb - 1312) * 256 + threadIdx.x;      // [0, 18432): 9 taps x 4 tiles x 512
        int tap = idx >> 11;
        int r = idx & 2047;
        int tile = r >> 9;
        int ln = (r >> 3) & 63;
        int j = r & 7;
        int mt = tile >> 1, kc = tile & 1;
        int n = mt * 16 + (ln & 15);
        int c = kc * 32 + (ln >> 4) * 8 + j;
        float v = (n < 18) ? Woff[(n * 64 + c) * 9 + tap] : 0.f;
        Woffb[idx] = f2bf(v);
    }
}

// ---- single fused kernel: offset-conv GEMM1 (M=32pad) -> LDS offsets ->
//      bilinear-sample GEMM2 (M=128). 64 px/block, B-frags register-direct,
//      A double-buffered in frag-major LDS (conflict-free), 1 barrier/tap. ----
__global__ __launch_bounds__(256, 4) void fused_kernel(
        const unsigned short* __restrict__ xt,     // [b][y][x][c] bf16
        const unsigned short* __restrict__ Wkb2,   // frag-major, 9*8192
        const unsigned short* __restrict__ Woffb,  // frag-major, 9*2048
        const float* __restrict__ boff,
        const float* __restrict__ bias,
        float* __restrict__ out) {
    __shared__ unsigned short As[2][8192];         // 32 KB
    __shared__ float offs[64][20];                 // 5 KB, 18 offset chans per px
    int tid = threadIdx.x;
    int wave = tid >> 6, lane = tid & 63;
    int frow = lane & 15, quad = lane >> 4;
    // XCD-aware remap: 2 whole batch images per XCD
    int bb = blockIdx.x;
    int xcd = bb & 7, idx = bb >> 3;
    int b = xcd * 2 + (idx >> 6);
    int pxBase = (idx & 63) * 64;
    int pl = wave * 16 + frow;                     // block-local pixel
    int px = pxBase + pl;
    int y = px >> 6, xx = px & 63;
    const char* img = (const char*)(xt + (size_t)b * 262144) + quad * 16;

    // boff values this lane will need for its offs-write
    float bv[2][4];
#pragma unroll
    for (int mt = 0; mt < 2; mt++)
#pragma unroll
        for (int rg = 0; rg < 4; rg++) {
            int n = mt * 16 + quad * 4 + rg;
            bv[mt][rg] = (n < 18) ? boff[n] : 0.f;
        }

    // ================= GEMM1: offset conv (zero-padded taps) =================
    floatx4 acc1[2];
    acc1[0] = (floatx4)(0.f); acc1[1] = (floatx4)(0.f);
    bf16x8 aw = *(const bf16x8*)(Woffb + tid * 8);
    *(bf16x8*)&As[0][tid * 8] = aw;
    for (int tap = 0; tap < 9; tap++) {
        if (tap < 8) aw = *(const bf16x8*)(Woffb + (tap + 1) * 2048 + tid * 8);
        __syncthreads();                           // As[tap&1] writes visible
        int ry = y + tap / 3 - 1, rx = xx + tap % 3 - 1;
        bool valid = (ry >= 0) & (ry < 64) & (rx >= 0) & (rx < 64);
        const char* src = img + ((ry * 64 + rx) << 7);
        const unsigned short* abuf = &As[tap & 1][0];
        bf16x8 bz = {};
#pragma unroll
        for (int kc = 0; kc < 2; kc++) {
            bf16x8 bfr = valid ? *(const bf16x8*)(src + kc * 64) : bz;
#pragma unroll
            for (int mt = 0; mt < 2; mt++) {
                bf16x8 af = *(const bf16x8*)&abuf[(mt * 2 + kc) * 512 + lane * 8];
                acc1[mt] = __builtin_amdgcn_mfma_f32_16x16x32_bf16(af, bfr, acc1[mt], 0, 0, 0);
            }
        }
        if (tap < 8) *(bf16x8*)&As[(tap + 1) & 1][tid * 8] = aw;
    }
    // D: col=frow(px), row=quad*4+rg (+mt*16) -> offset channel n of pixel pl
#pragma unroll
    for (int mt = 0; mt < 2; mt++)
#pragma unroll
        for (int rg = 0; rg < 4; rg++) {
            int n = mt * 16 + quad * 4 + rg;
            if (n < 18) offs[pl][n] = acc1[mt][rg] + bv[mt][rg];
        }

    // ================= GEMM2: bilinear sample + main conv =================
    floatx4 acc[8];
#pragma unroll
    for (int i = 0; i < 8; i++) acc[i] = (floatx4)(0.f);
    bf16x8 wk[4];
#pragma unroll
    for (int i = 0; i < 4; i++)
        wk[i] = *(const bf16x8*)(Wkb2 + i * 2048 + tid * 8);
    __syncthreads();                               // offs written; GEMM1 As reads done
#pragma unroll
    for (int i = 0; i < 4; i++)
        *(bf16x8*)&As[0][i * 2048 + tid * 8] = wk[i];

    for (int tap = 0; tap < 9; tap++) {
        if (tap < 8)
#pragma unroll
            for (int i = 0; i < 4; i++)
                wk[i] = *(const bf16x8*)(Wkb2 + (tap + 1) * 8192 + i * 2048 + tid * 8);
        __syncthreads();                           // As[tap&1] writes + (tap0) offs visible
        float orow = offs[pl][tap];
        float ocol = offs[pl][9 + tap];
        float pr = (float)(y + tap / 3 - 1) + orow;
        float pc = (float)(xx + tap % 3 - 1) + ocol;
        pr = fminf(fmaxf(pr, 0.f), 63.f);
        pc = fminf(fmaxf(pc, 0.f), 63.f);
        float fr = floorf(pr), fc = floorf(pc);
        float tr = pr - fr, tc = pc - fc;
        int r0 = (int)fr, c0 = (int)fc;
        int r1 = min(r0 + 1, 63), c1 = min(c0 + 1, 63);
        float w00 = (1.f - tr) * (1.f - tc);
        float w01 = (1.f - tr) * tc;
        float w10 = tr * (1.f - tc);
        float w11 = tr * tc;
        int o00 = (r0 * 64 + c0) * 128;
        int o01 = (r0 * 64 + c1) * 128;
        int o10 = (r1 * 64 + c0) * 128;
        int o11 = (r1 * 64 + c1) * 128;

        bf16x8 bfrag[2];
#pragma unroll
        for (int kc = 0; kc < 2; kc++) {
            int4 u00 = __builtin_bit_cast(int4, *(const bf16x8*)(img + o00 + kc * 64));
            int4 u01 = __builtin_bit_cast(int4, *(const bf16x8*)(img + o01 + kc * 64));
            int4 u10 = __builtin_bit_cast(int4, *(const bf16x8*)(img + o10 + kc * 64));
            int4 u11 = __builtin_bit_cast(int4, *(const bf16x8*)(img + o11 + kc * 64));
            int4 r;
#pragma unroll
            for (int wd = 0; wd < 4; wd++) {
                int a00 = (wd == 0) ? u00.x : (wd == 1) ? u00.y : (wd == 2) ? u00.z : u00.w;
                int a01 = (wd == 0) ? u01.x : (wd == 1) ? u01.y : (wd == 2) ? u01.z : u01.w;
                int a10 = (wd == 0) ? u10.x : (wd == 1) ? u10.y : (wd == 2) ? u10.z : u10.w;
                int a11 = (wd == 0) ? u11.x : (wd == 1) ? u11.y : (wd == 2) ? u11.z : u11.w;
                float vl = w00 * __uint_as_float((unsigned)a00 << 16)
                         + w01 * __uint_as_float((unsigned)a01 << 16)
                         + w10 * __uint_as_float((unsigned)a10 << 16)
                         + w11 * __uint_as_float((unsigned)a11 << 16);
                float vh = w00 * __uint_as_float((unsigned)a00 & 0xffff0000u)
                         + w01 * __uint_as_float((unsigned)a01 & 0xffff0000u)
                         + w10 * __uint_as_float((unsigned)a10 & 0xffff0000u)
                         + w11 * __uint_as_float((unsigned)a11 & 0xffff0000u);
                unsigned pk = __builtin_amdgcn_perm(
                    __float_as_uint(vh) + 0x8000u,
                    __float_as_uint(vl) + 0x8000u, 0x07060302u);
                if (wd == 0) r.x = (int)pk; else if (wd == 1) r.y = (int)pk;
                else if (wd == 2) r.z = (int)pk; else r.w = (int)pk;
            }
            bfrag[kc] = __builtin_bit_cast(bf16x8, r);
        }
        const unsigned short* abuf = &As[tap & 1][0];
#pragma unroll
        for (int kc = 0; kc < 2; kc++)
#pragma unroll
            for (int mt = 0; mt < 8; mt++) {
                bf16x8 af = *(const bf16x8*)&abuf[(mt * 2 + kc) * 512 + lane * 8];
                acc[mt] = __builtin_amdgcn_mfma_f32_16x16x32_bf16(af, bfrag[kc], acc[mt], 0, 0, 0);
            }
        if (tap < 8)
#pragma unroll
            for (int i = 0; i < 4; i++)
                *(bf16x8*)&As[(tap + 1) & 1][i * 2048 + tid * 8] = wk[i];
    }

    // --- epilogue: D col=frow (px), row=quad*4+rg (oc) ---
    float* outb = out + (size_t)b * 524288 + px;
#pragma unroll
    for (int mt = 0; mt < 8; mt++) {
#pragma unroll
        for (int rg = 0; rg < 4; rg++) {
            int oc = mt * 16 + quad * 4 + rg;
            outb[oc * 4096] = acc[mt][rg] + bias[oc];
        }
    }
}

extern "C" void kernel_launch(void* const* d_in, const int* in_sizes, int n_in,
                              void* d_out, int out_size, void* d_ws, size_t ws_size,
                              hipStream_t stream) {
    const float* x    = (const float*)d_in[0];
    const float* Woff = (const float*)d_in[1];
    const float* boff = (const float*)d_in[2];
    const float* Wk   = (const float*)d_in[3];
    const float* bk   = (const float*)d_in[4];
    float* out = (float*)d_out;

    char* ws = (char*)d_ws;
    unsigned short* xt    = (unsigned short*)ws;               // 8388608 B
    unsigned short* Wkb2  = (unsigned short*)(ws + 8388608);   // 147456 B
    unsigned short* Woffb = (unsigned short*)(ws + 8536064);   // 36864 B

    prep_all<<<1384, 256, 0, stream>>>(x, Wk, Woff, xt, Wkb2, Woffb);
    fused_kernel<<<1024, 256, 0, stream>>>(xt, Wkb2, Woffb, boff, bk, out);
}